// Round 8
// baseline (5181.999 us; speedup 1.0000x reference)
//
#include <hip/hip_runtime.h>
#include <hip/hip_fp16.h>

#define HIST 50

typedef __fp16 hf2 __attribute__((ext_vector_type(2)));
union U32H2 { unsigned u; hf2 h; };
__device__ __forceinline__ unsigned h2u(hf2 h){ U32H2 c; c.h = h; return c.u; }
__device__ __forceinline__ hf2 u2h(unsigned u){ U32H2 c; c.u = u; return c.h; }
__device__ __forceinline__ hf2 pkrtz(float a, float b){ return __builtin_amdgcn_cvt_pkrtz(a, b); }
// v_dot2_f32_f16 via builtin: d = a.lo*b.lo + a.hi*b.hi + c (f32 accumulate)
__device__ __forceinline__ float dot2(hf2 a, hf2 b, float c){ return __builtin_amdgcn_fdot2(a, b, c, false); }

__global__ void ue_fast(const int* __restrict__ nodes, const int* __restrict__ hitems,
                        const int* __restrict__ hrat, const int* __restrict__ hlen,
                        const float* __restrict__ u2e, const float* __restrict__ i2e,
                        const float* __restrict__ r2e,
                        const float* __restrict__ w1w, const float* __restrict__ w1b,
                        const float* __restrict__ w2w, const float* __restrict__ w2b,
                        const float* __restrict__ a1w, const float* __restrict__ a1b,
                        const float* __restrict__ a2w, const float* __restrict__ a2b,
                        const float* __restrict__ a3w, const float* __restrict__ a3b,
                        float* __restrict__ out, int n_nodes)
{
    const int lane = threadIdx.x;        // 64 threads = 1 wave per block

    // ---- LDS (single wave => __syncthreads is wave-local and cheap) ----
    __shared__ __align__(16) float    xa[128];        // f32 staging for x = [p;r]
    __shared__ __align__(16) float    ya[64];         // f32 staging for y / o / a1
    __shared__ __align__(16) unsigned xh[64];         // packed f16 x (128 vals)
    __shared__ __align__(16) unsigned yh[32];         // packed f16 64-vec
    __shared__ __align__(16) unsigned oh32[32];       // packed f16 o
    __shared__ __align__(16) unsigned ush[32];        // packed f16 u
    __shared__ __align__(16) float    osv[HIST * 64]; // o (f32) for final sum
    __shared__ __align__(16) float    sc[64];         // scores
    __shared__ __align__(16) float    attv[64];       // softmax weights

    // ---- weights into per-lane registers, f16x2 packed; lane j = output row j ----
    hf2 w1r[64], a1r[64], w2r[32], a2r[32];
    #pragma unroll
    for (int q = 0; q < 32; ++q) {
        const float4 v = *(const float4*)(w1w + lane*128 + 4*q);
        w1r[2*q]   = pkrtz(v.x, v.y);
        w1r[2*q+1] = pkrtz(v.z, v.w);
        const float4 u = *(const float4*)(a1w + lane*128 + 4*q);
        a1r[2*q]   = pkrtz(u.x, u.y);
        a1r[2*q+1] = pkrtz(u.z, u.w);
    }
    #pragma unroll
    for (int q = 0; q < 16; ++q) {
        const float4 v = *(const float4*)(w2w + lane*64 + 4*q);
        w2r[2*q]   = pkrtz(v.x, v.y);
        w2r[2*q+1] = pkrtz(v.z, v.w);
        const float4 u = *(const float4*)(a2w + lane*64 + 4*q);
        a2r[2*q]   = pkrtz(u.x, u.y);
        a2r[2*q+1] = pkrtz(u.z, u.w);
    }
    const float b1r    = w1b[lane];
    const float b2r    = w2b[lane];
    const float ab1r   = a1b[lane];
    const float ab2r   = a2b[lane];
    const float a3r    = a3w[lane];
    const float a3bias = a3b[0];

    for (int n = blockIdx.x; n < n_nodes; n += gridDim.x) {
        const int node = nodes[n];
        const int hl   = hlen[n];

        // ---- user embedding packed once per node ----
        ya[lane] = u2e[(long)node * 64 + lane];
        __syncthreads();
        if (lane < 32) {
            const float2 t = *(const float2*)&ya[2*lane];
            ush[lane] = h2u(pkrtz(t.x, t.y));
        }
        __syncthreads();

        for (int l = 0; l < hl; ++l) {   // l >= hl has softmax weight exactly 0: skip is exact
            const int item   = hitems[n*HIST + l];
            const int rating = hrat[n*HIST + l];

            // ---- stage + pack x = [p ; r] ----
            xa[lane]      = i2e[(long)item * 64 + lane];
            xa[64 + lane] = r2e[(long)rating * 64 + lane];
            __syncthreads();
            if (lane < 32) {
                const float2 t0 = *(const float2*)&xa[2*lane];
                xh[lane]      = h2u(pkrtz(t0.x, t0.y));
                const float2 t1 = *(const float2*)&xa[64 + 2*lane];
                xh[32 + lane] = h2u(pkrtz(t1.x, t1.y));
            }
            __syncthreads();

            // ---- layer 1: [128] -> [64] ----
            float c0 = 0.f, c1 = 0.f, c2 = 0.f, c3 = 0.f;
            #pragma unroll
            for (int q = 0; q < 16; ++q) {
                const uint4 hx = *(const uint4*)&xh[4*q];
                c0 = dot2(w1r[4*q+0], u2h(hx.x), c0);
                c1 = dot2(w1r[4*q+1], u2h(hx.y), c1);
                c2 = dot2(w1r[4*q+2], u2h(hx.z), c2);
                c3 = dot2(w1r[4*q+3], u2h(hx.w), c3);
            }
            const float yv = fmaxf(b1r + ((c0 + c1) + (c2 + c3)), 0.f);
            ya[lane] = yv;
            __syncthreads();
            if (lane < 32) {
                const float2 t = *(const float2*)&ya[2*lane];
                yh[lane] = h2u(pkrtz(t.x, t.y));
            }
            __syncthreads();

            // ---- layer 2: [64] -> [64] ----
            c0 = 0.f; c1 = 0.f; c2 = 0.f; c3 = 0.f;
            #pragma unroll
            for (int q = 0; q < 8; ++q) {
                const uint4 hy = *(const uint4*)&yh[4*q];
                c0 = dot2(w2r[4*q+0], u2h(hy.x), c0);
                c1 = dot2(w2r[4*q+1], u2h(hy.y), c1);
                c2 = dot2(w2r[4*q+2], u2h(hy.z), c2);
                c3 = dot2(w2r[4*q+3], u2h(hy.w), c3);
            }
            const float ov = fmaxf(b2r + ((c0 + c1) + (c2 + c3)), 0.f);
            osv[l*64 + lane] = ov;            // own column; no cross-lane dep
            ya[lane] = ov;
            __syncthreads();
            if (lane < 32) {
                const float2 t = *(const float2*)&ya[2*lane];
                oh32[lane] = h2u(pkrtz(t.x, t.y));
            }
            __syncthreads();

            // ---- att layer 1: [o ; u] (128) -> [64] ----
            c0 = 0.f; c1 = 0.f; c2 = 0.f; c3 = 0.f;
            #pragma unroll
            for (int q = 0; q < 8; ++q) {
                const uint4 ho = *(const uint4*)&oh32[4*q];
                c0 = dot2(a1r[4*q+0], u2h(ho.x), c0);
                c1 = dot2(a1r[4*q+1], u2h(ho.y), c1);
                c2 = dot2(a1r[4*q+2], u2h(ho.z), c2);
                c3 = dot2(a1r[4*q+3], u2h(ho.w), c3);
            }
            #pragma unroll
            for (int q = 0; q < 8; ++q) {
                const uint4 hu = *(const uint4*)&ush[4*q];
                c0 = dot2(a1r[32+4*q+0], u2h(hu.x), c0);
                c1 = dot2(a1r[32+4*q+1], u2h(hu.y), c1);
                c2 = dot2(a1r[32+4*q+2], u2h(hu.z), c2);
                c3 = dot2(a1r[32+4*q+3], u2h(hu.w), c3);
            }
            const float av1 = fmaxf(ab1r + ((c0 + c1) + (c2 + c3)), 0.f);
            ya[lane] = av1;
            __syncthreads();
            if (lane < 32) {
                const float2 t = *(const float2*)&ya[2*lane];
                yh[lane] = h2u(pkrtz(t.x, t.y));
            }
            __syncthreads();

            // ---- att layer 2: [64] -> [64] ----
            c0 = 0.f; c1 = 0.f; c2 = 0.f; c3 = 0.f;
            #pragma unroll
            for (int q = 0; q < 8; ++q) {
                const uint4 hy = *(const uint4*)&yh[4*q];
                c0 = dot2(a2r[4*q+0], u2h(hy.x), c0);
                c1 = dot2(a2r[4*q+1], u2h(hy.y), c1);
                c2 = dot2(a2r[4*q+2], u2h(hy.z), c2);
                c3 = dot2(a2r[4*q+3], u2h(hy.w), c3);
            }
            const float av2 = fmaxf(ab2r + ((c0 + c1) + (c2 + c3)), 0.f);

            // ---- att layer 3: [64] -> scalar (wave butterfly) ----
            float tt = av2 * a3r;
            #pragma unroll
            for (int off = 32; off; off >>= 1) tt += __shfl_xor(tt, off);
            if (lane == 0) sc[l] = tt + a3bias;
            // no barrier needed here: sc only read after the loop barrier below
        }
        __syncthreads();

        // ---- softmax over valid l (lane = l) ----
        const float NEG_INF = -__builtin_inff();
        const float s = (lane < hl) ? sc[lane] : NEG_INF;
        float m = s;
        #pragma unroll
        for (int off = 32; off; off >>= 1) m = fmaxf(m, __shfl_xor(m, off));
        const float e = (lane < hl) ? expf(s - m) : 0.f;
        float se = e;
        #pragma unroll
        for (int off = 32; off; off >>= 1) se += __shfl_xor(se, off);
        attv[lane] = e / se;
        __syncthreads();

        // ---- out_j = sum_l att_l * o[l][j]  (lane reads own column of osv) ----
        float part = 0.f;
        for (int l = 0; l < hl; ++l) {
            part += attv[l] * osv[l*64 + lane];
        }
        out[(long)n * 64 + lane] = part;
        __syncthreads();   // protect next iteration's staging overwrites
    }
}

extern "C" void kernel_launch(void* const* d_in, const int* in_sizes, int n_in,
                              void* d_out, int out_size, void* d_ws, size_t ws_size,
                              hipStream_t stream) {
    const int*   nodes  = (const int*)d_in[0];
    const int*   hitems = (const int*)d_in[1];
    const int*   hrat   = (const int*)d_in[2];
    const int*   hlenp  = (const int*)d_in[3];
    const float* u2e    = (const float*)d_in[4];
    const float* i2e    = (const float*)d_in[5];
    const float* r2e    = (const float*)d_in[6];
    const float* w1w    = (const float*)d_in[7];
    const float* w1b    = (const float*)d_in[8];
    const float* w2w    = (const float*)d_in[9];
    const float* w2b    = (const float*)d_in[10];
    const float* a1w    = (const float*)d_in[11];
    const float* a1b    = (const float*)d_in[12];
    const float* a2w    = (const float*)d_in[13];
    const float* a2b    = (const float*)d_in[14];
    const float* a3w    = (const float*)d_in[15];
    const float* a3b    = (const float*)d_in[16];
    float* out = (float*)d_out;

    const int n_nodes = in_sizes[0];
    const int blocks  = 2048;   // persistent 1-wave blocks; 8 nodes each
    ue_fast<<<dim3(blocks), dim3(64), 0, stream>>>(
        nodes, hitems, hrat, hlenp, u2e, i2e, r2e,
        w1w, w1b, w2w, w2b, a1w, a1b, a2w, a2b, a3w, a3b,
        out, n_nodes);
}

// Round 9
// 968.093 us; speedup vs baseline: 5.3528x; 5.3528x over previous
//
#include <hip/hip_runtime.h>
#include <hip/hip_fp16.h>

#define HIST 50

typedef __fp16 hf2 __attribute__((ext_vector_type(2)));
union U32H2 { unsigned u; hf2 h; };
__device__ __forceinline__ unsigned h2u(hf2 h){ U32H2 c; c.h = h; return c.u; }
__device__ __forceinline__ hf2 u2h(unsigned u){ U32H2 c; c.u = u; return c.h; }
__device__ __forceinline__ hf2 pkrtz(float a, float b){ return __builtin_amdgcn_cvt_pkrtz(a, b); }
// v_dot2_f32_f16 via builtin: d = a.lo*b.lo + a.hi*b.hi + c (f32 accumulate)
__device__ __forceinline__ float dot2(hf2 a, hf2 b, float c){ return __builtin_amdgcn_fdot2(a, b, c, false); }

__global__ __launch_bounds__(64, 1)   // 1-wave block, min 1 wave/EU -> allow ~512 VGPRs (weights stay resident)
void ue_fast(const int* __restrict__ nodes, const int* __restrict__ hitems,
             const int* __restrict__ hrat, const int* __restrict__ hlen,
             const float* __restrict__ u2e, const float* __restrict__ i2e,
             const float* __restrict__ r2e,
             const float* __restrict__ w1w, const float* __restrict__ w1b,
             const float* __restrict__ w2w, const float* __restrict__ w2b,
             const float* __restrict__ a1w, const float* __restrict__ a1b,
             const float* __restrict__ a2w, const float* __restrict__ a2b,
             const float* __restrict__ a3w, const float* __restrict__ a3b,
             float* __restrict__ out, int n_nodes)
{
    const int lane = threadIdx.x;        // 64 threads = 1 wave per block

    // ---- LDS (single wave => __syncthreads is wave-local and cheap) ----
    __shared__ __align__(16) float    xa[128];        // f32 staging for x = [p;r]
    __shared__ __align__(16) float    ya[64];         // f32 staging for y / o / a1
    __shared__ __align__(16) unsigned xh[64];         // packed f16 x (128 vals)
    __shared__ __align__(16) unsigned yh[32];         // packed f16 64-vec
    __shared__ __align__(16) unsigned oh32[32];       // packed f16 o
    __shared__ __align__(16) unsigned ush[32];        // packed f16 u
    __shared__ __align__(16) float    osv[HIST * 64]; // o (f32) for final sum
    __shared__ __align__(16) float    sc[64];         // scores
    __shared__ __align__(16) float    attv[64];       // softmax weights

    // ---- weights into per-lane registers, f16x2 packed; lane j = output row j ----
    hf2 w1r[64], a1r[64], w2r[32], a2r[32];
    #pragma unroll
    for (int q = 0; q < 32; ++q) {
        const float4 v = *(const float4*)(w1w + lane*128 + 4*q);
        w1r[2*q]   = pkrtz(v.x, v.y);
        w1r[2*q+1] = pkrtz(v.z, v.w);
        const float4 u = *(const float4*)(a1w + lane*128 + 4*q);
        a1r[2*q]   = pkrtz(u.x, u.y);
        a1r[2*q+1] = pkrtz(u.z, u.w);
    }
    #pragma unroll
    for (int q = 0; q < 16; ++q) {
        const float4 v = *(const float4*)(w2w + lane*64 + 4*q);
        w2r[2*q]   = pkrtz(v.x, v.y);
        w2r[2*q+1] = pkrtz(v.z, v.w);
        const float4 u = *(const float4*)(a2w + lane*64 + 4*q);
        a2r[2*q]   = pkrtz(u.x, u.y);
        a2r[2*q+1] = pkrtz(u.z, u.w);
    }
    const float b1r    = w1b[lane];
    const float b2r    = w2b[lane];
    const float ab1r   = a1b[lane];
    const float ab2r   = a2b[lane];
    const float a3r    = a3w[lane];
    const float a3bias = a3b[0];

    for (int n = blockIdx.x; n < n_nodes; n += gridDim.x) {
        const int node = nodes[n];
        const int hl   = hlen[n];

        // ---- user embedding packed once per node ----
        ya[lane] = u2e[(long)node * 64 + lane];
        __syncthreads();
        if (lane < 32) {
            const float2 t = *(const float2*)&ya[2*lane];
            ush[lane] = h2u(pkrtz(t.x, t.y));
        }
        __syncthreads();

        for (int l = 0; l < hl; ++l) {   // l >= hl has softmax weight exactly 0: skip is exact
            const int item   = hitems[n*HIST + l];
            const int rating = hrat[n*HIST + l];

            // ---- stage + pack x = [p ; r] ----
            xa[lane]      = i2e[(long)item * 64 + lane];
            xa[64 + lane] = r2e[(long)rating * 64 + lane];
            __syncthreads();
            if (lane < 32) {
                const float2 t0 = *(const float2*)&xa[2*lane];
                xh[lane]      = h2u(pkrtz(t0.x, t0.y));
                const float2 t1 = *(const float2*)&xa[64 + 2*lane];
                xh[32 + lane] = h2u(pkrtz(t1.x, t1.y));
            }
            __syncthreads();

            // ---- layer 1: [128] -> [64] ----
            float c0 = 0.f, c1 = 0.f, c2 = 0.f, c3 = 0.f;
            #pragma unroll
            for (int q = 0; q < 16; ++q) {
                const uint4 hx = *(const uint4*)&xh[4*q];
                c0 = dot2(w1r[4*q+0], u2h(hx.x), c0);
                c1 = dot2(w1r[4*q+1], u2h(hx.y), c1);
                c2 = dot2(w1r[4*q+2], u2h(hx.z), c2);
                c3 = dot2(w1r[4*q+3], u2h(hx.w), c3);
            }
            const float yv = fmaxf(b1r + ((c0 + c1) + (c2 + c3)), 0.f);
            ya[lane] = yv;
            __syncthreads();
            if (lane < 32) {
                const float2 t = *(const float2*)&ya[2*lane];
                yh[lane] = h2u(pkrtz(t.x, t.y));
            }
            __syncthreads();

            // ---- layer 2: [64] -> [64] ----
            c0 = 0.f; c1 = 0.f; c2 = 0.f; c3 = 0.f;
            #pragma unroll
            for (int q = 0; q < 8; ++q) {
                const uint4 hy = *(const uint4*)&yh[4*q];
                c0 = dot2(w2r[4*q+0], u2h(hy.x), c0);
                c1 = dot2(w2r[4*q+1], u2h(hy.y), c1);
                c2 = dot2(w2r[4*q+2], u2h(hy.z), c2);
                c3 = dot2(w2r[4*q+3], u2h(hy.w), c3);
            }
            const float ov = fmaxf(b2r + ((c0 + c1) + (c2 + c3)), 0.f);
            osv[l*64 + lane] = ov;            // own column; no cross-lane dep
            ya[lane] = ov;
            __syncthreads();
            if (lane < 32) {
                const float2 t = *(const float2*)&ya[2*lane];
                oh32[lane] = h2u(pkrtz(t.x, t.y));
            }
            __syncthreads();

            // ---- att layer 1: [o ; u] (128) -> [64] ----
            c0 = 0.f; c1 = 0.f; c2 = 0.f; c3 = 0.f;
            #pragma unroll
            for (int q = 0; q < 8; ++q) {
                const uint4 ho = *(const uint4*)&oh32[4*q];
                c0 = dot2(a1r[4*q+0], u2h(ho.x), c0);
                c1 = dot2(a1r[4*q+1], u2h(ho.y), c1);
                c2 = dot2(a1r[4*q+2], u2h(ho.z), c2);
                c3 = dot2(a1r[4*q+3], u2h(ho.w), c3);
            }
            #pragma unroll
            for (int q = 0; q < 8; ++q) {
                const uint4 hu = *(const uint4*)&ush[4*q];
                c0 = dot2(a1r[32+4*q+0], u2h(hu.x), c0);
                c1 = dot2(a1r[32+4*q+1], u2h(hu.y), c1);
                c2 = dot2(a1r[32+4*q+2], u2h(hu.z), c2);
                c3 = dot2(a1r[32+4*q+3], u2h(hu.w), c3);
            }
            const float av1 = fmaxf(ab1r + ((c0 + c1) + (c2 + c3)), 0.f);
            ya[lane] = av1;
            __syncthreads();
            if (lane < 32) {
                const float2 t = *(const float2*)&ya[2*lane];
                yh[lane] = h2u(pkrtz(t.x, t.y));
            }
            __syncthreads();

            // ---- att layer 2: [64] -> [64] ----
            c0 = 0.f; c1 = 0.f; c2 = 0.f; c3 = 0.f;
            #pragma unroll
            for (int q = 0; q < 8; ++q) {
                const uint4 hy = *(const uint4*)&yh[4*q];
                c0 = dot2(a2r[4*q+0], u2h(hy.x), c0);
                c1 = dot2(a2r[4*q+1], u2h(hy.y), c1);
                c2 = dot2(a2r[4*q+2], u2h(hy.z), c2);
                c3 = dot2(a2r[4*q+3], u2h(hy.w), c3);
            }
            const float av2 = fmaxf(ab2r + ((c0 + c1) + (c2 + c3)), 0.f);

            // ---- att layer 3: [64] -> scalar (wave butterfly) ----
            float tt = av2 * a3r;
            #pragma unroll
            for (int off = 32; off; off >>= 1) tt += __shfl_xor(tt, off);
            if (lane == 0) sc[l] = tt + a3bias;
            // sc only read after the barrier below
        }
        __syncthreads();

        // ---- softmax over valid l (lane = l) ----
        const float NEG_INF = -__builtin_inff();
        const float s = (lane < hl) ? sc[lane] : NEG_INF;
        float m = s;
        #pragma unroll
        for (int off = 32; off; off >>= 1) m = fmaxf(m, __shfl_xor(m, off));
        const float e = (lane < hl) ? expf(s - m) : 0.f;
        float se = e;
        #pragma unroll
        for (int off = 32; off; off >>= 1) se += __shfl_xor(se, off);
        attv[lane] = e / se;
        __syncthreads();

        // ---- out_j = sum_l att_l * o[l][j]  (lane reads own column of osv) ----
        float part = 0.f;
        for (int l = 0; l < hl; ++l) {
            part += attv[l] * osv[l*64 + lane];
        }
        out[(long)n * 64 + lane] = part;
        __syncthreads();   // protect next iteration's staging overwrites
    }
}

extern "C" void kernel_launch(void* const* d_in, const int* in_sizes, int n_in,
                              void* d_out, int out_size, void* d_ws, size_t ws_size,
                              hipStream_t stream) {
    const int*   nodes  = (const int*)d_in[0];
    const int*   hitems = (const int*)d_in[1];
    const int*   hrat   = (const int*)d_in[2];
    const int*   hlenp  = (const int*)d_in[3];
    const float* u2e    = (const float*)d_in[4];
    const float* i2e    = (const float*)d_in[5];
    const float* r2e    = (const float*)d_in[6];
    const float* w1w    = (const float*)d_in[7];
    const float* w1b    = (const float*)d_in[8];
    const float* w2w    = (const float*)d_in[9];
    const float* w2b    = (const float*)d_in[10];
    const float* a1w    = (const float*)d_in[11];
    const float* a1b    = (const float*)d_in[12];
    const float* a2w    = (const float*)d_in[13];
    const float* a2b    = (const float*)d_in[14];
    const float* a3w    = (const float*)d_in[15];
    const float* a3b    = (const float*)d_in[16];
    float* out = (float*)d_out;

    const int n_nodes = in_sizes[0];
    const int blocks  = 4096;   // 1-wave blocks; ~4 nodes each (oversubscribed for hl balance)
    ue_fast<<<dim3(blocks), dim3(64), 0, stream>>>(
        nodes, hitems, hrat, hlenp, u2e, i2e, r2e,
        w1w, w1b, w2w, w2b, a1w, a1b, a2w, a2b, a3w, a3b,
        out, n_nodes);
}

// Round 10
// 730.526 us; speedup vs baseline: 7.0935x; 1.3252x over previous
//
#include <hip/hip_runtime.h>
#include <hip/hip_fp16.h>

#define HIST 50

typedef __fp16 hf;
typedef __fp16 hf2 __attribute__((ext_vector_type(2)));
union U32H2 { unsigned u; hf2 h; };
__device__ __forceinline__ unsigned h2u(hf2 h){ U32H2 c; c.h = h; return c.u; }
__device__ __forceinline__ hf2 u2h(unsigned u){ U32H2 c; c.u = u; return c.h; }
__device__ __forceinline__ hf2 pkrtz(float a, float b){ return __builtin_amdgcn_cvt_pkrtz(a, b); }
// v_dot2_f32_f16: d = a.lo*b.lo + a.hi*b.hi + c (f32 accumulate)
__device__ __forceinline__ float dot2(hf2 a, hf2 b, float c){ return __builtin_amdgcn_fdot2(a, b, c, false); }

__global__ __launch_bounds__(64, 1)   // 1-wave block; allow high VGPR so weights stay resident
void ue_v2(const int* __restrict__ nodes, const int* __restrict__ hitems,
           const int* __restrict__ hrat, const int* __restrict__ hlen,
           const float* __restrict__ u2e, const float* __restrict__ i2e,
           const float* __restrict__ r2e,
           const float* __restrict__ w1w, const float* __restrict__ w1b,
           const float* __restrict__ w2w, const float* __restrict__ w2b,
           const float* __restrict__ a1w, const float* __restrict__ a1b,
           const float* __restrict__ a2w, const float* __restrict__ a2b,
           const float* __restrict__ a3w, const float* __restrict__ a3b,
           float* __restrict__ out, int n_nodes)
{
    const int lane = threadIdx.x;     // 64 threads = 1 wave

    __shared__ __align__(16) float    uax[64];          // user embedding f32 (ubias input)
    __shared__ __align__(16) int      ih[HIST];         // item indices for this node
    __shared__ __align__(16) int      rh[HIST];         // rating indices
    __shared__ __align__(16) unsigned xh[64];           // packed f16 x = [p;r]
    __shared__ __align__(16) unsigned yh[32];           // packed f16 64-vec (y1 / a1)
    __shared__ __align__(16) unsigned osp[HIST*32];     // packed f16 o per pair
    __shared__ __align__(16) float    sc[64];           // scores
    __shared__ __align__(16) float    attv[64];         // softmax weights

    // ---- resident weights (lane j = output row j), f16x2 packed ----
    hf2 w1r[64], a1o[32], w2r[32], a2r[32];
    #pragma unroll
    for (int q = 0; q < 32; ++q) {
        const float4 v = *(const float4*)(w1w + lane*128 + 4*q);
        w1r[2*q]   = pkrtz(v.x, v.y);
        w1r[2*q+1] = pkrtz(v.z, v.w);
    }
    #pragma unroll
    for (int q = 0; q < 16; ++q) {
        const float4 u = *(const float4*)(a1w + lane*128 + 4*q);   // o-half: cols 0..63
        a1o[2*q]   = pkrtz(u.x, u.y);
        a1o[2*q+1] = pkrtz(u.z, u.w);
        const float4 v = *(const float4*)(w2w + lane*64 + 4*q);
        w2r[2*q]   = pkrtz(v.x, v.y);
        w2r[2*q+1] = pkrtz(v.z, v.w);
        const float4 a = *(const float4*)(a2w + lane*64 + 4*q);
        a2r[2*q]   = pkrtz(a.x, a.y);
        a2r[2*q+1] = pkrtz(a.z, a.w);
    }
    const float b1r    = w1b[lane];
    const float b2r    = w2b[lane];
    const float ab1r   = a1b[lane];
    const float ab2r   = a2b[lane];
    const float a3r    = a3w[lane];
    const float a3bias = a3b[0];

    for (int n = blockIdx.x; n < n_nodes; n += gridDim.x) {
        const int node = nodes[n];
        const int hl   = hlen[n];

        // ---- per-node staging: u (f32) + history indices ----
        uax[lane] = u2e[(long)node * 64 + lane];
        if (lane < HIST) {
            ih[lane] = hitems[n*HIST + lane];
            rh[lane] = hrat[n*HIST + lane];
        }
        __syncthreads();

        // ---- ubias_j = ab1_j + sum_k u_k * A1[j][64+k]  (u-half folded per node) ----
        float u0 = ab1r, u1 = 0.f, u2 = 0.f, u3 = 0.f;
        #pragma unroll
        for (int t = 0; t < 16; ++t) {
            const float4 v = *(const float4*)(a1w + lane*128 + 64 + 4*t);
            u0 = fmaf(v.x, uax[4*t+0], u0);
            u1 = fmaf(v.y, uax[4*t+1], u1);
            u2 = fmaf(v.z, uax[4*t+2], u2);
            u3 = fmaf(v.w, uax[4*t+3], u3);
        }
        const float ubias = (u0 + u1) + (u2 + u3);

        // ---- prefetch first pair's embedding rows ----
        float p_cur = i2e[(long)ih[0] * 64 + lane];
        float r_cur = r2e[(long)rh[0] * 64 + lane];

        for (int l = 0; l < hl; ++l) {   // l >= hl has softmax weight exactly 0: skip is exact
            // prefetch next pair (hidden under this pair's compute)
            float p_nx = p_cur, r_nx = r_cur;
            if (l + 1 < hl) {
                p_nx = i2e[(long)ih[l+1] * 64 + lane];
                r_nx = r2e[(long)rh[l+1] * 64 + lane];
            }

            // ---- pack x = [p ; r] via pair shuffle (1 LDS write, no f32 round-trip) ----
            {
                const float po = __shfl_xor(p_cur, 1);
                const float ro = __shfl_xor(r_cur, 1);
                const hf2 pp = pkrtz((lane&1) ? po : p_cur, (lane&1) ? p_cur : po);
                const hf2 rp = pkrtz((lane&1) ? ro : r_cur, (lane&1) ? r_cur : ro);
                xh[(lane>>1)]      = h2u(pp);   // duplicate same-value writes: benign
                xh[32 + (lane>>1)] = h2u(rp);
            }
            __syncthreads();

            // ---- layer 1: [128] -> [64] ----
            float c0 = 0.f, c1 = 0.f, c2 = 0.f, c3 = 0.f;
            #pragma unroll
            for (int q = 0; q < 16; ++q) {
                const uint4 hx = *(const uint4*)&xh[4*q];
                c0 = dot2(w1r[4*q+0], u2h(hx.x), c0);
                c1 = dot2(w1r[4*q+1], u2h(hx.y), c1);
                c2 = dot2(w1r[4*q+2], u2h(hx.z), c2);
                c3 = dot2(w1r[4*q+3], u2h(hx.w), c3);
            }
            const float yv = fmaxf(b1r + ((c0 + c1) + (c2 + c3)), 0.f);
            {
                const float yo = __shfl_xor(yv, 1);
                yh[lane>>1] = h2u(pkrtz((lane&1) ? yo : yv, (lane&1) ? yv : yo));
            }
            __syncthreads();

            // ---- layer 2: [64] -> [64] ----
            c0 = 0.f; c1 = 0.f; c2 = 0.f; c3 = 0.f;
            #pragma unroll
            for (int q = 0; q < 8; ++q) {
                const uint4 hy = *(const uint4*)&yh[4*q];
                c0 = dot2(w2r[4*q+0], u2h(hy.x), c0);
                c1 = dot2(w2r[4*q+1], u2h(hy.y), c1);
                c2 = dot2(w2r[4*q+2], u2h(hy.z), c2);
                c3 = dot2(w2r[4*q+3], u2h(hy.w), c3);
            }
            const float ov = fmaxf(b2r + ((c0 + c1) + (c2 + c3)), 0.f);
            {   // RNE pack for o (feeds final output directly)
                const float oo = __shfl_xor(ov, 1);
                const float lo = (lane&1) ? oo : ov;
                const float hi = (lane&1) ? ov : oo;
                hf2 op; op[0] = (hf)lo; op[1] = (hf)hi;
                osp[l*32 + (lane>>1)] = h2u(op);
            }
            __syncthreads();

            // ---- att layer 1 (o-half only; u folded into ubias): [64] -> [64] ----
            c0 = 0.f; c1 = 0.f; c2 = 0.f; c3 = 0.f;
            const unsigned* const opk = &osp[l*32];
            #pragma unroll
            for (int q = 0; q < 8; ++q) {
                const uint4 ho = *(const uint4*)&opk[4*q];
                c0 = dot2(a1o[4*q+0], u2h(ho.x), c0);
                c1 = dot2(a1o[4*q+1], u2h(ho.y), c1);
                c2 = dot2(a1o[4*q+2], u2h(ho.z), c2);
                c3 = dot2(a1o[4*q+3], u2h(ho.w), c3);
            }
            const float av1 = fmaxf(ubias + ((c0 + c1) + (c2 + c3)), 0.f);
            {
                const float ao = __shfl_xor(av1, 1);
                yh[lane>>1] = h2u(pkrtz((lane&1) ? ao : av1, (lane&1) ? av1 : ao));
            }
            __syncthreads();

            // ---- att layer 2: [64] -> [64] ----
            c0 = 0.f; c1 = 0.f; c2 = 0.f; c3 = 0.f;
            #pragma unroll
            for (int q = 0; q < 8; ++q) {
                const uint4 hy = *(const uint4*)&yh[4*q];
                c0 = dot2(a2r[4*q+0], u2h(hy.x), c0);
                c1 = dot2(a2r[4*q+1], u2h(hy.y), c1);
                c2 = dot2(a2r[4*q+2], u2h(hy.z), c2);
                c3 = dot2(a2r[4*q+3], u2h(hy.w), c3);
            }
            const float av2 = fmaxf(ab2r + ((c0 + c1) + (c2 + c3)), 0.f);

            // ---- att layer 3: [64] -> scalar (wave butterfly) ----
            float tt = av2 * a3r;
            #pragma unroll
            for (int off = 32; off; off >>= 1) tt += __shfl_xor(tt, off);
            if (lane == 0) sc[l] = tt + a3bias;

            p_cur = p_nx; r_cur = r_nx;
        }
        __syncthreads();

        // ---- softmax over valid l (lane = l) ----
        const float NEG_INF = -__builtin_inff();
        const float s = (lane < hl) ? sc[lane] : NEG_INF;
        float m = s;
        #pragma unroll
        for (int off = 32; off; off >>= 1) m = fmaxf(m, __shfl_xor(m, off));
        const float e = (lane < hl) ? expf(s - m) : 0.f;
        float se = e;
        #pragma unroll
        for (int off = 32; off; off >>= 1) se += __shfl_xor(se, off);
        attv[lane] = e / se;
        __syncthreads();

        // ---- out_j = sum_l att_l * o[l][j]  (o from packed f16) ----
        float part = 0.f;
        for (int l = 0; l < hl; ++l) {
            const hf2 hh = u2h(osp[l*32 + (lane>>1)]);
            part = fmaf(attv[l], (float)hh[lane & 1], part);
        }
        out[(long)n * 64 + lane] = part;
        __syncthreads();   // protect next node's staging overwrites
    }
}

extern "C" void kernel_launch(void* const* d_in, const int* in_sizes, int n_in,
                              void* d_out, int out_size, void* d_ws, size_t ws_size,
                              hipStream_t stream) {
    const int*   nodes  = (const int*)d_in[0];
    const int*   hitems = (const int*)d_in[1];
    const int*   hrat   = (const int*)d_in[2];
    const int*   hlenp  = (const int*)d_in[3];
    const float* u2e    = (const float*)d_in[4];
    const float* i2e    = (const float*)d_in[5];
    const float* r2e    = (const float*)d_in[6];
    const float* w1w    = (const float*)d_in[7];
    const float* w1b    = (const float*)d_in[8];
    const float* w2w    = (const float*)d_in[9];
    const float* w2b    = (const float*)d_in[10];
    const float* a1w    = (const float*)d_in[11];
    const float* a1b    = (const float*)d_in[12];
    const float* a2w    = (const float*)d_in[13];
    const float* a2b    = (const float*)d_in[14];
    const float* a3w    = (const float*)d_in[15];
    const float* a3b    = (const float*)d_in[16];
    float* out = (float*)d_out;

    const int n_nodes = in_sizes[0];
    const int blocks  = 8192;   // 1-wave blocks; ~2 nodes each (ragged-hl tail smoothing)
    ue_v2<<<dim3(blocks), dim3(64), 0, stream>>>(
        nodes, hitems, hrat, hlenp, u2e, i2e, r2e,
        w1w, w1b, w2w, w2b, a1w, a1b, a2w, a2b, a3w, a3b,
        out, n_nodes);
}

// Round 11
// 458.330 us; speedup vs baseline: 11.3063x; 1.5939x over previous
//
#include <hip/hip_runtime.h>
#include <hip/hip_fp16.h>

#define HIST 50

typedef __fp16 hf;
typedef __fp16 hf2 __attribute__((ext_vector_type(2)));
union U32H2 { unsigned u; hf2 h; };
__device__ __forceinline__ unsigned h2u(hf2 h){ U32H2 c; c.h = h; return c.u; }
__device__ __forceinline__ hf2 u2h(unsigned u){ U32H2 c; c.u = u; return c.h; }
__device__ __forceinline__ hf2 pkrtz(float a, float b){ return __builtin_amdgcn_cvt_pkrtz(a, b); }
// v_dot2_f32_f16: d = a.lo*b.lo + a.hi*b.hi + c (f32 accumulate)
__device__ __forceinline__ float dot2(hf2 a, hf2 b, float c){ return __builtin_amdgcn_fdot2(a, b, c, false); }

__global__ __launch_bounds__(64, 2)   // 2 waves/SIMD: 256-VGPR budget, co-resident wave hides LDS/barrier latency
void ue_v2(const int* __restrict__ nodes, const int* __restrict__ hitems,
           const int* __restrict__ hrat, const int* __restrict__ hlen,
           const float* __restrict__ u2e, const float* __restrict__ i2e,
           const float* __restrict__ r2e,
           const float* __restrict__ w1w, const float* __restrict__ w1b,
           const float* __restrict__ w2w, const float* __restrict__ w2b,
           const float* __restrict__ a1w, const float* __restrict__ a1b,
           const float* __restrict__ a2w, const float* __restrict__ a2b,
           const float* __restrict__ a3w, const float* __restrict__ a3b,
           float* __restrict__ out, int n_nodes)
{
    const int lane = threadIdx.x;     // 64 threads = 1 wave

    __shared__ __align__(16) float    uax[64];          // user embedding f32 (ubias input)
    __shared__ __align__(16) int      ih[HIST];         // item indices for this node
    __shared__ __align__(16) int      rh[HIST];         // rating indices
    __shared__ __align__(16) unsigned xh[64];           // packed f16 x = [p;r]
    __shared__ __align__(16) unsigned yh[32];           // packed f16 64-vec (y1 / a1)
    __shared__ __align__(16) unsigned osp[HIST*32];     // packed f16 o per pair
    __shared__ __align__(16) float    sc[64];           // scores
    __shared__ __align__(16) float    attv[64];         // softmax weights

    // ---- resident weights (lane j = output row j), f16x2 packed ----
    hf2 w1r[64], a1o[32], w2r[32], a2r[32];
    #pragma unroll
    for (int q = 0; q < 32; ++q) {
        const float4 v = *(const float4*)(w1w + lane*128 + 4*q);
        w1r[2*q]   = pkrtz(v.x, v.y);
        w1r[2*q+1] = pkrtz(v.z, v.w);
    }
    #pragma unroll
    for (int q = 0; q < 16; ++q) {
        const float4 u = *(const float4*)(a1w + lane*128 + 4*q);   // o-half: cols 0..63
        a1o[2*q]   = pkrtz(u.x, u.y);
        a1o[2*q+1] = pkrtz(u.z, u.w);
        const float4 v = *(const float4*)(w2w + lane*64 + 4*q);
        w2r[2*q]   = pkrtz(v.x, v.y);
        w2r[2*q+1] = pkrtz(v.z, v.w);
        const float4 a = *(const float4*)(a2w + lane*64 + 4*q);
        a2r[2*q]   = pkrtz(a.x, a.y);
        a2r[2*q+1] = pkrtz(a.z, a.w);
    }
    const float b1r    = w1b[lane];
    const float b2r    = w2b[lane];
    const float ab1r   = a1b[lane];
    const float ab2r   = a2b[lane];
    const float a3r    = a3w[lane];
    const float a3bias = a3b[0];

    for (int n = blockIdx.x; n < n_nodes; n += gridDim.x) {
        const int node = nodes[n];
        const int hl   = hlen[n];

        // ---- per-node staging: u (f32) + history indices ----
        uax[lane] = u2e[(long)node * 64 + lane];
        if (lane < HIST) {
            ih[lane] = hitems[n*HIST + lane];
            rh[lane] = hrat[n*HIST + lane];
        }
        __syncthreads();

        // ---- ubias_j = ab1_j + sum_k u_k * A1[j][64+k]  (u-half folded per node) ----
        float u0 = ab1r, u1 = 0.f, u2 = 0.f, u3 = 0.f;
        #pragma unroll
        for (int t = 0; t < 16; ++t) {
            const float4 v = *(const float4*)(a1w + lane*128 + 64 + 4*t);
            u0 = fmaf(v.x, uax[4*t+0], u0);
            u1 = fmaf(v.y, uax[4*t+1], u1);
            u2 = fmaf(v.z, uax[4*t+2], u2);
            u3 = fmaf(v.w, uax[4*t+3], u3);
        }
        const float ubias = (u0 + u1) + (u2 + u3);

        // ---- prefetch first pair's embedding rows ----
        float p_cur = i2e[(long)ih[0] * 64 + lane];
        float r_cur = r2e[(long)rh[0] * 64 + lane];

        for (int l = 0; l < hl; ++l) {   // l >= hl has softmax weight exactly 0: skip is exact
            // prefetch next pair (hidden under this pair's compute)
            float p_nx = p_cur, r_nx = r_cur;
            if (l + 1 < hl) {
                p_nx = i2e[(long)ih[l+1] * 64 + lane];
                r_nx = r2e[(long)rh[l+1] * 64 + lane];
            }

            // ---- pack x = [p ; r] via pair shuffle (1 LDS write, no f32 round-trip) ----
            {
                const float po = __shfl_xor(p_cur, 1);
                const float ro = __shfl_xor(r_cur, 1);
                const hf2 pp = pkrtz((lane&1) ? po : p_cur, (lane&1) ? p_cur : po);
                const hf2 rp = pkrtz((lane&1) ? ro : r_cur, (lane&1) ? r_cur : ro);
                xh[(lane>>1)]      = h2u(pp);   // duplicate same-value writes: benign
                xh[32 + (lane>>1)] = h2u(rp);
            }
            __syncthreads();

            // ---- layer 1: [128] -> [64] ----
            float c0 = 0.f, c1 = 0.f, c2 = 0.f, c3 = 0.f;
            #pragma unroll
            for (int q = 0; q < 16; ++q) {
                const uint4 hx = *(const uint4*)&xh[4*q];
                c0 = dot2(w1r[4*q+0], u2h(hx.x), c0);
                c1 = dot2(w1r[4*q+1], u2h(hx.y), c1);
                c2 = dot2(w1r[4*q+2], u2h(hx.z), c2);
                c3 = dot2(w1r[4*q+3], u2h(hx.w), c3);
            }
            const float yv = fmaxf(b1r + ((c0 + c1) + (c2 + c3)), 0.f);
            {
                const float yo = __shfl_xor(yv, 1);
                yh[lane>>1] = h2u(pkrtz((lane&1) ? yo : yv, (lane&1) ? yv : yo));
            }
            __syncthreads();

            // ---- layer 2: [64] -> [64] ----
            c0 = 0.f; c1 = 0.f; c2 = 0.f; c3 = 0.f;
            #pragma unroll
            for (int q = 0; q < 8; ++q) {
                const uint4 hy = *(const uint4*)&yh[4*q];
                c0 = dot2(w2r[4*q+0], u2h(hy.x), c0);
                c1 = dot2(w2r[4*q+1], u2h(hy.y), c1);
                c2 = dot2(w2r[4*q+2], u2h(hy.z), c2);
                c3 = dot2(w2r[4*q+3], u2h(hy.w), c3);
            }
            const float ov = fmaxf(b2r + ((c0 + c1) + (c2 + c3)), 0.f);
            {   // RNE pack for o (feeds final output directly)
                const float oo = __shfl_xor(ov, 1);
                const float lo = (lane&1) ? oo : ov;
                const float hi = (lane&1) ? ov : oo;
                hf2 op; op[0] = (hf)lo; op[1] = (hf)hi;
                osp[l*32 + (lane>>1)] = h2u(op);
            }
            __syncthreads();

            // ---- att layer 1 (o-half only; u folded into ubias): [64] -> [64] ----
            c0 = 0.f; c1 = 0.f; c2 = 0.f; c3 = 0.f;
            const unsigned* const opk = &osp[l*32];
            #pragma unroll
            for (int q = 0; q < 8; ++q) {
                const uint4 ho = *(const uint4*)&opk[4*q];
                c0 = dot2(a1o[4*q+0], u2h(ho.x), c0);
                c1 = dot2(a1o[4*q+1], u2h(ho.y), c1);
                c2 = dot2(a1o[4*q+2], u2h(ho.z), c2);
                c3 = dot2(a1o[4*q+3], u2h(ho.w), c3);
            }
            const float av1 = fmaxf(ubias + ((c0 + c1) + (c2 + c3)), 0.f);
            {
                const float ao = __shfl_xor(av1, 1);
                yh[lane>>1] = h2u(pkrtz((lane&1) ? ao : av1, (lane&1) ? av1 : ao));
            }
            __syncthreads();

            // ---- att layer 2: [64] -> [64] ----
            c0 = 0.f; c1 = 0.f; c2 = 0.f; c3 = 0.f;
            #pragma unroll
            for (int q = 0; q < 8; ++q) {
                const uint4 hy = *(const uint4*)&yh[4*q];
                c0 = dot2(a2r[4*q+0], u2h(hy.x), c0);
                c1 = dot2(a2r[4*q+1], u2h(hy.y), c1);
                c2 = dot2(a2r[4*q+2], u2h(hy.z), c2);
                c3 = dot2(a2r[4*q+3], u2h(hy.w), c3);
            }
            const float av2 = fmaxf(ab2r + ((c0 + c1) + (c2 + c3)), 0.f);

            // ---- att layer 3: [64] -> scalar (wave butterfly) ----
            float tt = av2 * a3r;
            #pragma unroll
            for (int off = 32; off; off >>= 1) tt += __shfl_xor(tt, off);
            if (lane == 0) sc[l] = tt + a3bias;

            p_cur = p_nx; r_cur = r_nx;
        }
        __syncthreads();

        // ---- softmax over valid l (lane = l) ----
        const float NEG_INF = -__builtin_inff();
        const float s = (lane < hl) ? sc[lane] : NEG_INF;
        float m = s;
        #pragma unroll
        for (int off = 32; off; off >>= 1) m = fmaxf(m, __shfl_xor(m, off));
        const float e = (lane < hl) ? expf(s - m) : 0.f;
        float se = e;
        #pragma unroll
        for (int off = 32; off; off >>= 1) se += __shfl_xor(se, off);
        attv[lane] = e / se;
        __syncthreads();

        // ---- out_j = sum_l att_l * o[l][j]  (o from packed f16) ----
        float part = 0.f;
        for (int l = 0; l < hl; ++l) {
            const hf2 hh = u2h(osp[l*32 + (lane>>1)]);
            part = fmaf(attv[l], (float)hh[lane & 1], part);
        }
        out[(long)n * 64 + lane] = part;
        __syncthreads();   // protect next node's staging overwrites
    }
}

extern "C" void kernel_launch(void* const* d_in, const int* in_sizes, int n_in,
                              void* d_out, int out_size, void* d_ws, size_t ws_size,
                              hipStream_t stream) {
    const int*   nodes  = (const int*)d_in[0];
    const int*   hitems = (const int*)d_in[1];
    const int*   hrat   = (const int*)d_in[2];
    const int*   hlenp  = (const int*)d_in[3];
    const float* u2e    = (const float*)d_in[4];
    const float* i2e    = (const float*)d_in[5];
    const float* r2e    = (const float*)d_in[6];
    const float* w1w    = (const float*)d_in[7];
    const float* w1b    = (const float*)d_in[8];
    const float* w2w    = (const float*)d_in[9];
    const float* w2b    = (const float*)d_in[10];
    const float* a1w    = (const float*)d_in[11];
    const float* a1b    = (const float*)d_in[12];
    const float* a2w    = (const float*)d_in[13];
    const float* a2b    = (const float*)d_in[14];
    const float* a3w    = (const float*)d_in[15];
    const float* a3b    = (const float*)d_in[16];
    float* out = (float*)d_out;

    const int n_nodes = in_sizes[0];
    const int blocks  = 8192;   // 1-wave blocks; ~2 nodes each (ragged-hl tail smoothing)
    ue_v2<<<dim3(blocks), dim3(64), 0, stream>>>(
        nodes, hitems, hrat, hlenp, u2e, i2e, r2e,
        w1w, w1b, w2w, w2b, a1w, a1b, a2w, a2b, a3w, a3b,
        out, n_nodes);
}

// Round 12
// 354.054 us; speedup vs baseline: 14.6362x; 1.2945x over previous
//
#include <hip/hip_runtime.h>
#include <hip/hip_fp16.h>

#define HIST 50

typedef __fp16 hf;
typedef __fp16 hf2 __attribute__((ext_vector_type(2)));
typedef __fp16 h8  __attribute__((ext_vector_type(8)));
typedef float  f4  __attribute__((ext_vector_type(4)));

union U32H2 { unsigned u; hf2 h; };
__device__ __forceinline__ unsigned h2u(hf2 h){ U32H2 c; c.h=h; return c.u; }
__device__ __forceinline__ hf2 pkrtz(float a,float b){ return __builtin_amdgcn_cvt_pkrtz(a,b); }

__device__ __forceinline__ h8 mk8(hf2 a, hf2 b, hf2 c, hf2 d){
    h8 r; r[0]=a[0]; r[1]=a[1]; r[2]=b[0]; r[3]=b[1]; r[4]=c[0]; r[5]=c[1]; r[6]=d[0]; r[7]=d[1]; return r;
}
// 8 consecutive f32 at W[row + kb .. +7] -> f16x8 fragment
__device__ __forceinline__ h8 ldfrag(const float* W, long row, int kb){
    const float4 v0 = *(const float4*)(W + row + kb);
    const float4 v1 = *(const float4*)(W + row + kb + 4);
    return mk8(pkrtz(v0.x,v0.y), pkrtz(v0.z,v0.w), pkrtz(v1.x,v1.y), pkrtz(v1.z,v1.w));
}
__device__ __forceinline__ f4 mfma16(h8 a, h8 b, f4 c){
    return __builtin_amdgcn_mfma_f32_16x16x32_f16(a,b,c,0,0,0);
}
__device__ __forceinline__ f4 relu4(f4 v){
    v[0]=fmaxf(v[0],0.f); v[1]=fmaxf(v[1],0.f); v[2]=fmaxf(v[2],0.f); v[3]=fmaxf(v[3],0.f); return v;
}

// store C-layout tile (acc[nt], col=16nt+(lane&15), rows (lane>>4)*4+r) as swizzled f16 [16 rows][64 cols]
__device__ __forceinline__ void store_ct(unsigned short* base, const f4* acc, int lane){
    const int m0    = (lane>>4)*4;
    const int ceven = lane & 14;
    const bool odd  = lane & 1;
    #pragma unroll
    for (int nt = 0; nt < 4; ++nt){
        const int c0 = 16*nt + ceven;
        #pragma unroll
        for (int r = 0; r < 4; ++r){
            const float mine = acc[nt][r];
            const float oth  = __shfl_xor(mine, 1);     // executed by ALL lanes
            if (!odd){
                const int m    = m0 + r;
                const int gp   = (c0 >> 3) ^ (m & 7);   // 16B-granule XOR swizzle
                const int byte = m*128 + gp*16 + ((2*c0) & 15);
                *(unsigned*)((char*)base + byte) = h2u(pkrtz(mine, oth));
            }
        }
    }
}
// read A-fragment (row=lane&15, k=32*kt+8*(lane>>4)+i) from swizzled f16 [16][64]
__device__ __forceinline__ h8 read_af(const unsigned short* base, int lane, int kt){
    const int row  = lane & 15;
    const int gp   = (4*kt + (lane>>4)) ^ (row & 7);
    const int byte = row*128 + gp*16;
    return *(const h8*)((const char*)base + byte);
}

__global__ __launch_bounds__(64, 2)
void ue_mfma(const int* __restrict__ nodes, const int* __restrict__ hitems,
             const int* __restrict__ hrat, const int* __restrict__ hlen,
             const float* __restrict__ u2e, const float* __restrict__ i2e,
             const float* __restrict__ r2e,
             const float* __restrict__ w1w, const float* __restrict__ w1b,
             const float* __restrict__ w2w, const float* __restrict__ w2b,
             const float* __restrict__ a1w, const float* __restrict__ a1b,
             const float* __restrict__ a2w, const float* __restrict__ a2b,
             const float* __restrict__ a3w, const float* __restrict__ a3b,
             float* __restrict__ out, int n_nodes)
{
    const int lane = threadIdx.x;            // 1 wave per block
    const int nidx = lane & 15;              // col index within fragment
    const int kgrp = lane >> 4;              // k-chunk group

    __shared__ __align__(16) unsigned short xfer[16*64];     // transpose buffer
    __shared__ __align__(16) unsigned short o_all[4*16*64];  // o per tile (f16 swizzled)
    __shared__ __align__(16) float uax[64];
    __shared__ __align__(16) float ubias_lds[64];
    __shared__ __align__(16) int   ih[HIST];
    __shared__ __align__(16) int   rh[HIST];
    __shared__ __align__(16) float sc[64];
    __shared__ __align__(16) float attv[64];

    // ---- weight fragments: B[k][n]=W[n][k]; lane: n=16nt+nidx, k=32kt+8*kgrp+i ----
    h8 W1f[4][4], W2f[2][4], A1f[2][4], A2f[2][4];
    #pragma unroll
    for (int nt = 0; nt < 4; ++nt){
        const long row128 = (long)(16*nt + nidx) * 128;
        const long row64  = (long)(16*nt + nidx) * 64;
        #pragma unroll
        for (int kt = 0; kt < 4; ++kt)
            W1f[kt][nt] = ldfrag(w1w, row128, 32*kt + 8*kgrp);
        #pragma unroll
        for (int kt = 0; kt < 2; ++kt){
            W2f[kt][nt] = ldfrag(w2w, row64,  32*kt + 8*kgrp);
            A1f[kt][nt] = ldfrag(a1w, row128, 32*kt + 8*kgrp);   // o-half (cols 0..63)
            A2f[kt][nt] = ldfrag(a2w, row64,  32*kt + 8*kgrp);
        }
    }
    float b1c[4], b2c[4], ab2c[4], a3c[4];
    #pragma unroll
    for (int nt = 0; nt < 4; ++nt){
        b1c[nt]  = w1b[16*nt + nidx];
        b2c[nt]  = w2b[16*nt + nidx];
        ab2c[nt] = a2b[16*nt + nidx];
        a3c[nt]  = a3w[16*nt + nidx];
    }
    const float ab1r = a1b[lane];

    for (int n = blockIdx.x; n < n_nodes; n += gridDim.x) {
        __syncthreads();   // previous node's LDS reads fully drained
        const int node = nodes[n];
        const int hl   = hlen[n];

        uax[lane] = u2e[(long)node * 64 + lane];
        if (lane < HIST) {
            ih[lane] = hitems[n*HIST + lane];
            rh[lane] = hrat[n*HIST + lane];
        }
        __syncthreads();

        // ubias_j = ab1_j + sum_k u_k * A1[j][64+k]  (u-half of att1, folded per node)
        float u0 = ab1r, u1 = 0.f, u2 = 0.f, u3 = 0.f;
        #pragma unroll
        for (int t = 0; t < 16; ++t) {
            const float4 v = *(const float4*)(a1w + (long)lane*128 + 64 + 4*t);
            u0 = fmaf(v.x, uax[4*t+0], u0);
            u1 = fmaf(v.y, uax[4*t+1], u1);
            u2 = fmaf(v.z, uax[4*t+2], u2);
            u3 = fmaf(v.w, uax[4*t+3], u3);
        }
        ubias_lds[lane] = (u0 + u1) + (u2 + u3);
        __syncthreads();
        float ubc[4];
        #pragma unroll
        for (int nt = 0; nt < 4; ++nt) ubc[nt] = ubias_lds[16*nt + nidx];

        const int tiles = (hl + 15) >> 4;
        for (int t = 0; t < tiles; ++t) {
            // ---- gather X fragments (A-layout) straight from global ----
            int p = t*16 + nidx; if (p >= hl) p = hl - 1;   // clamp pad rows (masked later)
            const long irow = (long)ih[p] * 64;
            const long rrow = (long)rh[p] * 64;
            const int  kb   = 8 * kgrp;
            h8 Xf[4];
            Xf[0] = ldfrag(i2e, irow, kb);
            Xf[1] = ldfrag(i2e, irow, 32 + kb);
            Xf[2] = ldfrag(r2e, rrow, kb);
            Xf[3] = ldfrag(r2e, rrow, 32 + kb);

            // ---- layer 1: [16x128] @ [128x64] ----
            f4 acc[4];
            #pragma unroll
            for (int nt = 0; nt < 4; ++nt){
                f4 c = { b1c[nt], b1c[nt], b1c[nt], b1c[nt] };
                #pragma unroll
                for (int kt = 0; kt < 4; ++kt) c = mfma16(Xf[kt], W1f[kt][nt], c);
                acc[nt] = relu4(c);
            }
            store_ct(xfer, acc, lane);
            __syncthreads();
            h8 yf0 = read_af(xfer, lane, 0), yf1 = read_af(xfer, lane, 1);

            // ---- layer 2: [16x64] @ [64x64] -> o ----
            #pragma unroll
            for (int nt = 0; nt < 4; ++nt){
                f4 c = { b2c[nt], b2c[nt], b2c[nt], b2c[nt] };
                c = mfma16(yf0, W2f[0][nt], c);
                c = mfma16(yf1, W2f[1][nt], c);
                acc[nt] = relu4(c);
            }
            store_ct(o_all + t*1024, acc, lane);
            __syncthreads();
            h8 of0 = read_af(o_all + t*1024, lane, 0), of1 = read_af(o_all + t*1024, lane, 1);

            // ---- att layer 1 (o-half; u folded in ubias) ----
            #pragma unroll
            for (int nt = 0; nt < 4; ++nt){
                f4 c = { ubc[nt], ubc[nt], ubc[nt], ubc[nt] };
                c = mfma16(of0, A1f[0][nt], c);
                c = mfma16(of1, A1f[1][nt], c);
                acc[nt] = relu4(c);
            }
            store_ct(xfer, acc, lane);   // xfer reads at yf done before o_all barrier
            __syncthreads();
            h8 af0 = read_af(xfer, lane, 0), af1 = read_af(xfer, lane, 1);

            // ---- att layer 2 ----
            #pragma unroll
            for (int nt = 0; nt < 4; ++nt){
                f4 c = { ab2c[nt], ab2c[nt], ab2c[nt], ab2c[nt] };
                c = mfma16(af0, A2f[0][nt], c);
                c = mfma16(af1, A2f[1][nt], c);
                acc[nt] = relu4(c);
            }
            // ---- score = a2 . a3w  (att3_b dropped: softmax shift-invariant) ----
            f4 s = { 0.f, 0.f, 0.f, 0.f };
            #pragma unroll
            for (int nt = 0; nt < 4; ++nt){
                s[0] = fmaf(acc[nt][0], a3c[nt], s[0]);
                s[1] = fmaf(acc[nt][1], a3c[nt], s[1]);
                s[2] = fmaf(acc[nt][2], a3c[nt], s[2]);
                s[3] = fmaf(acc[nt][3], a3c[nt], s[3]);
            }
            #pragma unroll
            for (int off = 1; off <= 8; off <<= 1){
                s[0] += __shfl_xor(s[0], off);
                s[1] += __shfl_xor(s[1], off);
                s[2] += __shfl_xor(s[2], off);
                s[3] += __shfl_xor(s[3], off);
            }
            if (nidx == 0){
                const int m0 = kgrp * 4;
                sc[t*16 + m0 + 0] = s[0];
                sc[t*16 + m0 + 1] = s[1];
                sc[t*16 + m0 + 2] = s[2];
                sc[t*16 + m0 + 3] = s[3];
            }
            __syncthreads();   // tile end: xfer/o_all/sc all settled
        }

        // ---- softmax over valid l (lane = l) ----
        const float NEG_INF = -__builtin_inff();
        const float sv = (lane < hl) ? sc[lane] : NEG_INF;
        float m = sv;
        #pragma unroll
        for (int off = 32; off; off >>= 1) m = fmaxf(m, __shfl_xor(m, off));
        const float e = (lane < hl) ? expf(sv - m) : 0.f;
        float se = e;
        #pragma unroll
        for (int off = 32; off; off >>= 1) se += __shfl_xor(se, off);
        attv[lane] = e / se;
        __syncthreads();

        // ---- out_j = sum_l att_l * o[l][j]  (swizzled f16 read) ----
        float part = 0.f;
        const int gpj = lane >> 3;
        const int oj  = (2*lane) & 15;
        for (int l = 0; l < hl; ++l){
            const float al  = attv[l];
            const int   row = l & 15;
            const int   byte = (l >> 4)*2048 + row*128 + ((gpj ^ (row & 7))*16) + oj;
            const hf hv = *(const hf*)((const char*)o_all + byte);
            part = fmaf(al, (float)hv, part);
        }
        out[(long)n * 64 + lane] = part;
    }
}

extern "C" void kernel_launch(void* const* d_in, const int* in_sizes, int n_in,
                              void* d_out, int out_size, void* d_ws, size_t ws_size,
                              hipStream_t stream) {
    const int*   nodes  = (const int*)d_in[0];
    const int*   hitems = (const int*)d_in[1];
    const int*   hrat   = (const int*)d_in[2];
    const int*   hlenp  = (const int*)d_in[3];
    const float* u2e    = (const float*)d_in[4];
    const float* i2e    = (const float*)d_in[5];
    const float* r2e    = (const float*)d_in[6];
    const float* w1w    = (const float*)d_in[7];
    const float* w1b    = (const float*)d_in[8];
    const float* w2w    = (const float*)d_in[9];
    const float* w2b    = (const float*)d_in[10];
    const float* a1w    = (const float*)d_in[11];
    const float* a1b    = (const float*)d_in[12];
    const float* a2w    = (const float*)d_in[13];
    const float* a2b    = (const float*)d_in[14];
    const float* a3w    = (const float*)d_in[15];
    const float* a3b    = (const float*)d_in[16];
    float* out = (float*)d_out;

    const int n_nodes = in_sizes[0];
    const int blocks  = 8192;   // 1-wave blocks, grid-stride (~2 nodes each)
    ue_mfma<<<dim3(blocks), dim3(64), 0, stream>>>(
        nodes, hitems, hrat, hlenp, u2e, i2e, r2e,
        w1w, w1b, w2w, w2b, a1w, a1b, a2w, a2b, a3w, a3b,
        out, n_nodes);
}

// Round 13
// 282.167 us; speedup vs baseline: 18.3650x; 1.2548x over previous
//
#include <hip/hip_runtime.h>
#include <hip/hip_fp16.h>

#define HIST 50

typedef __fp16 hf;
typedef __fp16 hf2 __attribute__((ext_vector_type(2)));
typedef __fp16 h8  __attribute__((ext_vector_type(8)));
typedef float  f4  __attribute__((ext_vector_type(4)));

union U32H2 { unsigned u; hf2 h; };
__device__ __forceinline__ unsigned h2u(hf2 h){ U32H2 c; c.h=h; return c.u; }
__device__ __forceinline__ hf2 pkrtz(float a,float b){ return __builtin_amdgcn_cvt_pkrtz(a,b); }

__device__ __forceinline__ h8 mk8(hf2 a, hf2 b, hf2 c, hf2 d){
    h8 r; r[0]=a[0]; r[1]=a[1]; r[2]=b[0]; r[3]=b[1]; r[4]=c[0]; r[5]=c[1]; r[6]=d[0]; r[7]=d[1]; return r;
}
// 8 consecutive f32 at W[row + kb .. +7] -> f16x8 fragment
__device__ __forceinline__ h8 ldfrag(const float* W, long row, int kb){
    const float4 v0 = *(const float4*)(W + row + kb);
    const float4 v1 = *(const float4*)(W + row + kb + 4);
    return mk8(pkrtz(v0.x,v0.y), pkrtz(v0.z,v0.w), pkrtz(v1.x,v1.y), pkrtz(v1.z,v1.w));
}
__device__ __forceinline__ f4 mfma16(h8 a, h8 b, f4 c){
    return __builtin_amdgcn_mfma_f32_16x16x32_f16(a,b,c,0,0,0);
}
__device__ __forceinline__ f4 relu4(f4 v){
    v[0]=fmaxf(v[0],0.f); v[1]=fmaxf(v[1],0.f); v[2]=fmaxf(v[2],0.f); v[3]=fmaxf(v[3],0.f); return v;
}

// store C-layout tile (acc[nt], col=16nt+(lane&15), rows (lane>>4)*4+r) as swizzled f16 [16 rows][64 cols]
__device__ __forceinline__ void store_ct(unsigned short* base, const f4* acc, int lane){
    const int m0    = (lane>>4)*4;
    const int ceven = lane & 14;
    const bool odd  = lane & 1;
    #pragma unroll
    for (int nt = 0; nt < 4; ++nt){
        const int c0 = 16*nt + ceven;
        #pragma unroll
        for (int r = 0; r < 4; ++r){
            const float mine = acc[nt][r];
            const float oth  = __shfl_xor(mine, 1);     // executed by ALL lanes
            if (!odd){
                const int m    = m0 + r;
                const int gp   = (c0 >> 3) ^ (m & 7);   // 16B-granule XOR swizzle
                const int byte = m*128 + gp*16 + ((2*c0) & 15);
                *(unsigned*)((char*)base + byte) = h2u(pkrtz(mine, oth));
            }
        }
    }
}
// read A-fragment (row=lane&15, k=32*kt+8*(lane>>4)+i) from swizzled f16 [16][64]
__device__ __forceinline__ h8 read_af(const unsigned short* base, int lane, int kt){
    const int row  = lane & 15;
    const int gp   = (4*kt + (lane>>4)) ^ (row & 7);
    const int byte = row*128 + gp*16;
    return *(const h8*)((const char*)base + byte);
}

__global__ __launch_bounds__(64, 1)   // 512-reg unified budget: weights live in VGPR+AGPR, NO scratch spill
void ue_mfma(const int* __restrict__ nodes, const int* __restrict__ hitems,
             const int* __restrict__ hrat, const int* __restrict__ hlen,
             const float* __restrict__ u2e, const float* __restrict__ i2e,
             const float* __restrict__ r2e,
             const float* __restrict__ w1w, const float* __restrict__ w1b,
             const float* __restrict__ w2w, const float* __restrict__ w2b,
             const float* __restrict__ a1w, const float* __restrict__ a1b,
             const float* __restrict__ a2w, const float* __restrict__ a2b,
             const float* __restrict__ a3w, const float* __restrict__ a3b,
             float* __restrict__ out, int n_nodes)
{
    const int lane = threadIdx.x;            // 1 wave per block
    const int nidx = lane & 15;              // col index within fragment
    const int kgrp = lane >> 4;              // k-chunk group

    __shared__ __align__(16) unsigned short xfer[16*64];     // transpose buffer
    __shared__ __align__(16) unsigned short o_all[4*16*64];  // o per tile (f16 swizzled)
    __shared__ __align__(16) float uax[64];
    __shared__ __align__(16) float ubias_lds[64];
    __shared__ __align__(16) int   ih[HIST];
    __shared__ __align__(16) int   rh[HIST];
    __shared__ __align__(16) float sc[64];
    __shared__ __align__(16) float attv[64];

    // ---- weight fragments: B[k][n]=W[n][k]; lane: n=16nt+nidx, k=32kt+8*kgrp+i ----
    h8 W1f[4][4], W2f[2][4], A1f[2][4], A2f[2][4];
    #pragma unroll
    for (int nt = 0; nt < 4; ++nt){
        const long row128 = (long)(16*nt + nidx) * 128;
        const long row64  = (long)(16*nt + nidx) * 64;
        #pragma unroll
        for (int kt = 0; kt < 4; ++kt)
            W1f[kt][nt] = ldfrag(w1w, row128, 32*kt + 8*kgrp);
        #pragma unroll
        for (int kt = 0; kt < 2; ++kt){
            W2f[kt][nt] = ldfrag(w2w, row64,  32*kt + 8*kgrp);
            A1f[kt][nt] = ldfrag(a1w, row128, 32*kt + 8*kgrp);   // o-half (cols 0..63)
            A2f[kt][nt] = ldfrag(a2w, row64,  32*kt + 8*kgrp);
        }
    }
    float b1c[4], b2c[4], ab2c[4], a3c[4];
    #pragma unroll
    for (int nt = 0; nt < 4; ++nt){
        b1c[nt]  = w1b[16*nt + nidx];
        b2c[nt]  = w2b[16*nt + nidx];
        ab2c[nt] = a2b[16*nt + nidx];
        a3c[nt]  = a3w[16*nt + nidx];
    }
    const float ab1r = a1b[lane];

    for (int n = blockIdx.x; n < n_nodes; n += gridDim.x) {
        __syncthreads();   // previous node's LDS reads fully drained
        const int node = nodes[n];
        const int hl   = hlen[n];

        uax[lane] = u2e[(long)node * 64 + lane];
        if (lane < HIST) {
            ih[lane] = hitems[n*HIST + lane];
            rh[lane] = hrat[n*HIST + lane];
        }
        __syncthreads();

        // ubias_j = ab1_j + sum_k u_k * A1[j][64+k]  (u-half of att1, folded per node)
        float u0 = ab1r, u1 = 0.f, u2 = 0.f, u3 = 0.f;
        #pragma unroll
        for (int t = 0; t < 16; ++t) {
            const float4 v = *(const float4*)(a1w + (long)lane*128 + 64 + 4*t);
            u0 = fmaf(v.x, uax[4*t+0], u0);
            u1 = fmaf(v.y, uax[4*t+1], u1);
            u2 = fmaf(v.z, uax[4*t+2], u2);
            u3 = fmaf(v.w, uax[4*t+3], u3);
        }
        ubias_lds[lane] = (u0 + u1) + (u2 + u3);
        __syncthreads();
        float ubc[4];
        #pragma unroll
        for (int nt = 0; nt < 4; ++nt) ubc[nt] = ubias_lds[16*nt + nidx];

        const int tiles = (hl + 15) >> 4;
        for (int t = 0; t < tiles; ++t) {
            // ---- gather X fragments (A-layout) straight from global ----
            int p = t*16 + nidx; if (p >= hl) p = hl - 1;   // clamp pad rows (masked later)
            const long irow = (long)ih[p] * 64;
            const long rrow = (long)rh[p] * 64;
            const int  kb   = 8 * kgrp;
            h8 Xf[4];
            Xf[0] = ldfrag(i2e, irow, kb);
            Xf[1] = ldfrag(i2e, irow, 32 + kb);
            Xf[2] = ldfrag(r2e, rrow, kb);
            Xf[3] = ldfrag(r2e, rrow, 32 + kb);

            // ---- layer 1: [16x128] @ [128x64] ----
            f4 acc[4];
            #pragma unroll
            for (int nt = 0; nt < 4; ++nt){
                f4 c = { b1c[nt], b1c[nt], b1c[nt], b1c[nt] };
                #pragma unroll
                for (int kt = 0; kt < 4; ++kt) c = mfma16(Xf[kt], W1f[kt][nt], c);
                acc[nt] = relu4(c);
            }
            store_ct(xfer, acc, lane);
            __syncthreads();
            h8 yf0 = read_af(xfer, lane, 0), yf1 = read_af(xfer, lane, 1);

            // ---- layer 2: [16x64] @ [64x64] -> o ----
            #pragma unroll
            for (int nt = 0; nt < 4; ++nt){
                f4 c = { b2c[nt], b2c[nt], b2c[nt], b2c[nt] };
                c = mfma16(yf0, W2f[0][nt], c);
                c = mfma16(yf1, W2f[1][nt], c);
                acc[nt] = relu4(c);
            }
            store_ct(o_all + t*1024, acc, lane);
            __syncthreads();
            h8 of0 = read_af(o_all + t*1024, lane, 0), of1 = read_af(o_all + t*1024, lane, 1);

            // ---- att layer 1 (o-half; u folded in ubias) ----
            #pragma unroll
            for (int nt = 0; nt < 4; ++nt){
                f4 c = { ubc[nt], ubc[nt], ubc[nt], ubc[nt] };
                c = mfma16(of0, A1f[0][nt], c);
                c = mfma16(of1, A1f[1][nt], c);
                acc[nt] = relu4(c);
            }
            store_ct(xfer, acc, lane);   // xfer reads at yf done before o_all barrier
            __syncthreads();
            h8 af0 = read_af(xfer, lane, 0), af1 = read_af(xfer, lane, 1);

            // ---- att layer 2 ----
            #pragma unroll
            for (int nt = 0; nt < 4; ++nt){
                f4 c = { ab2c[nt], ab2c[nt], ab2c[nt], ab2c[nt] };
                c = mfma16(af0, A2f[0][nt], c);
                c = mfma16(af1, A2f[1][nt], c);
                acc[nt] = relu4(c);
            }
            // ---- score = a2 . a3w  (att3_b dropped: softmax shift-invariant) ----
            f4 s = { 0.f, 0.f, 0.f, 0.f };
            #pragma unroll
            for (int nt = 0; nt < 4; ++nt){
                s[0] = fmaf(acc[nt][0], a3c[nt], s[0]);
                s[1] = fmaf(acc[nt][1], a3c[nt], s[1]);
                s[2] = fmaf(acc[nt][2], a3c[nt], s[2]);
                s[3] = fmaf(acc[nt][3], a3c[nt], s[3]);
            }
            #pragma unroll
            for (int off = 1; off <= 8; off <<= 1){
                s[0] += __shfl_xor(s[0], off);
                s[1] += __shfl_xor(s[1], off);
                s[2] += __shfl_xor(s[2], off);
                s[3] += __shfl_xor(s[3], off);
            }
            if (nidx == 0){
                const int m0 = kgrp * 4;
                sc[t*16 + m0 + 0] = s[0];
                sc[t*16 + m0 + 1] = s[1];
                sc[t*16 + m0 + 2] = s[2];
                sc[t*16 + m0 + 3] = s[3];
            }
            __syncthreads();   // tile end: xfer/o_all/sc all settled
        }

        // ---- softmax over valid l (lane = l) ----
        const float NEG_INF = -__builtin_inff();
        const float sv = (lane < hl) ? sc[lane] : NEG_INF;
        float m = sv;
        #pragma unroll
        for (int off = 32; off; off >>= 1) m = fmaxf(m, __shfl_xor(m, off));
        const float e = (lane < hl) ? expf(sv - m) : 0.f;
        float se = e;
        #pragma unroll
        for (int off = 32; off; off >>= 1) se += __shfl_xor(se, off);
        attv[lane] = e / se;
        __syncthreads();

        // ---- out_j = sum_l att_l * o[l][j]  (swizzled f16 read) ----
        float part = 0.f;
        const int gpj = lane >> 3;
        const int oj  = (2*lane) & 15;
        for (int l = 0; l < hl; ++l){
            const float al  = attv[l];
            const int   row = l & 15;
            const int   byte = (l >> 4)*2048 + row*128 + ((gpj ^ (row & 7))*16) + oj;
            const hf hv = *(const hf*)((const char*)o_all + byte);
            part = fmaf(al, (float)hv, part);
        }
        out[(long)n * 64 + lane] = part;
    }
}

extern "C" void kernel_launch(void* const* d_in, const int* in_sizes, int n_in,
                              void* d_out, int out_size, void* d_ws, size_t ws_size,
                              hipStream_t stream) {
    const int*   nodes  = (const int*)d_in[0];
    const int*   hitems = (const int*)d_in[1];
    const int*   hrat   = (const int*)d_in[2];
    const int*   hlenp  = (const int*)d_in[3];
    const float* u2e    = (const float*)d_in[4];
    const float* i2e    = (const float*)d_in[5];
    const float* r2e    = (const float*)d_in[6];
    const float* w1w    = (const float*)d_in[7];
    const float* w1b    = (const float*)d_in[8];
    const float* w2w    = (const float*)d_in[9];
    const float* w2b    = (const float*)d_in[10];
    const float* a1w    = (const float*)d_in[11];
    const float* a1b    = (const float*)d_in[12];
    const float* a2w    = (const float*)d_in[13];
    const float* a2b    = (const float*)d_in[14];
    const float* a3w    = (const float*)d_in[15];
    const float* a3b    = (const float*)d_in[16];
    float* out = (float*)d_out;

    const int n_nodes = in_sizes[0];
    const int blocks  = 8192;   // 1-wave blocks, grid-stride (~2 nodes each)
    ue_mfma<<<dim3(blocks), dim3(64), 0, stream>>>(
        nodes, hitems, hrat, hlenp, u2e, i2e, r2e,
        w1w, w1b, w2w, w2b, a1w, a1b, a2w, a2b, a3w, a3b,
        out, n_nodes);
}